// Round 8
// baseline (2493.436 us; speedup 1.0000x reference)
//
#include <hip/hip_runtime.h>
#include <math.h>

#define BT 256
#define LT 256
#define KT 128
#define HT 256
#define LOSS_IDX ((size_t)BT*LT*KT)
#define PRED_IDX (LOSS_IDX + 1)
#define LDP 1280   // P row: [gammah 256 | alpha 128 | gipre 768 | zpre 128] f16
#define GH0 0
#define AL0 256
#define GI0 384
#define ZP0 1152

typedef _Float16 h2 __attribute__((ext_vector_type(2)));
typedef _Float16 f16x8 __attribute__((ext_vector_type(8)));
typedef float f32x4 __attribute__((ext_vector_type(4)));

__device__ __forceinline__ float fd2(h2 a, h2 b, float c){
#if __has_builtin(__builtin_amdgcn_fdot2)
  return __builtin_amdgcn_fdot2(a, b, c, false);
#else
  return c + (float)a[0]*(float)b[0] + (float)a[1]*(float)b[1];
#endif
}
__device__ __forceinline__ h2 lo2(f16x8 v){ return __builtin_shufflevector(v,v,0,1); }
__device__ __forceinline__ h2 p1v(f16x8 v){ return __builtin_shufflevector(v,v,2,3); }
__device__ __forceinline__ h2 p2v(f16x8 v){ return __builtin_shufflevector(v,v,4,5); }
__device__ __forceinline__ h2 p3v(f16x8 v){ return __builtin_shufflevector(v,v,6,7); }
__device__ __forceinline__ float sigf(float v){ return 1.0f/(1.0f + __expf(-v)); }
__device__ __forceinline__ float tanh_fast(float v){
  float a = fminf(fabsf(v), 15.0f);
  float e2 = __expf(2.0f*a);
  float r = (e2 - 1.0f)/(e2 + 1.0f);
  return copysignf(r, v);
}
__device__ __forceinline__ float f16bits(unsigned u, int hi){
  union { unsigned short s; _Float16 h; } c;
  c.s = (unsigned short)(hi ? (u >> 16) : (u & 0xffff));
  return (float)c.h;
}

// ---------- packing kernels ----------
__global__ void pack_cast(const float* __restrict__ src, _Float16* __restrict__ dst,
                          int J, int Kd, int diag, int total){
  int idx = blockIdx.x*256 + threadIdx.x;
  if (idx >= total) return;
  float v = src[idx];
  if (diag && (idx / Kd) == (idx % Kd)) v = 0.0f;
  dst[idx] = (_Float16)v;
}
__global__ void pack_rowchunks(const float* __restrict__ src, _Float16* __restrict__ dst,
                               int J, int K, int total){
  int idx = blockIdx.x*256 + threadIdx.x;
  if (idx >= total) return;
  int j = idx % J, c = idx / J;
  #pragma unroll
  for (int e = 0; e < 8; ++e)
    dst[(size_t)idx*8 + e] = (_Float16)src[(size_t)j*K + c*8 + e];
}
__global__ void pack_col(const float* __restrict__ src, _Float16* __restrict__ dst,
                         int J, int Kc, int ld, int diag, int total){
  int idx = blockIdx.x*256 + threadIdx.x;
  if (idx >= total) return;
  int j = idx % J, k = idx / J;
  float v = src[(size_t)j*ld + k];
  if (diag && j == k) v = 0.0f;
  dst[idx] = (_Float16)v;
}
// Wihc pair layout: dst h2[(k*384 + m)] = {W_ih[m][k], W_ih[m+384][k]}, k<128, m<384
__global__ void pack_colpair(const float* __restrict__ src, _Float16* __restrict__ dst,
                             int total){
  int idx = blockIdx.x*256 + threadIdx.x;
  if (idx >= total) return;
  int k = idx / 384, m = idx % 384;
  dst[(size_t)2*idx]     = (_Float16)src[(size_t)m*(2*KT) + k];
  dst[(size_t)2*idx + 1] = (_Float16)src[(size_t)(m + 384)*(2*KT) + k];
}

// ---------- scan: deltas + GEMM inputs ----------
__global__ __launch_bounds__(128) void scan_kernel(
    const float* __restrict__ x, const float* __restrict__ mask, const float* __restrict__ ts,
    const float* __restrict__ W_gx, const float* __restrict__ b_gx,
    const int* __restrict__ record_num,
    _Float16* __restrict__ deltas, _Float16* __restrict__ Agx, _Float16* __restrict__ U)
{
  int b = blockIdx.x, k = threadIdx.x;
  int rn = record_num[b];
  float gxd = W_gx[(size_t)k*KT + k];
  float bgx = b_gx[k];
  float d = 1.0f, tsp = 0.0f;
  for (int t0 = 0; t0 < LT; t0 += 8){
    float xv[8], mv[8], tsv[8];
    #pragma unroll
    for (int u = 0; u < 8; ++u){
      size_t off = ((size_t)b*LT + t0 + u)*KT + k;
      xv[u] = x[off]; mv[u] = mask[off];
      tsv[u] = ts[(size_t)b*LT + t0 + u];
    }
    #pragma unroll
    for (int u = 0; u < 8; ++u){
      int t = t0 + u;
      if (t > 0){
        float gap = fabsf(tsv[u] - (u ? tsv[u-1] : tsp));
        d = gap + (1.0f - mv[u])*d;
      }
      float e = (t < rn) ? 1.0f : 0.0f;
      float dev = d * e;
      size_t row = (size_t)b*LT + t;
      deltas[row*KT + k] = (_Float16)dev;
      float gx = __expf(-fmaxf(fmaf(dev, gxd, bgx), 0.0f));
      Agx[row*2*KT + k]      = (_Float16)gx;
      Agx[row*2*KT + KT + k] = (_Float16)mv[u];
      U[row*2*KT + k]        = (_Float16)(mv[u]*xv[u]);
      U[row*2*KT + KT + k]   = (_Float16)mv[u];
    }
    tsp = tsv[7];
  }
}

__global__ void msum_kernel(const float* __restrict__ mask, float* __restrict__ msumInv){
  __shared__ float red[256];
  int t = blockIdx.x;
  float acc = 0.0f;
  for (int i = threadIdx.x; i < BT*KT; i += 256){
    int b = i >> 7, k = i & 127;
    acc += mask[((size_t)b*LT + t)*KT + k];
  }
  red[threadIdx.x] = acc; __syncthreads();
  for (int s = 128; s > 0; s >>= 1){
    if (threadIdx.x < s) red[threadIdx.x] += red[threadIdx.x + s];
    __syncthreads();
  }
  if (threadIdx.x == 0) msumInv[t] = 1.0f/(red[0] + 1e-5f);
}

// ---------- MFMA GEMM ----------
__global__ __launch_bounds__(256) void gemm_f16(
    const _Float16* __restrict__ A, long ldA, int K,
    const _Float16* __restrict__ B, long ldB,
    _Float16* __restrict__ C, long colofs,
    const float* __restrict__ bias, int op)
{
  const int w = threadIdx.x >> 6, lane = threadIdx.x & 63;
  const int ml = lane & 15, quad = lane >> 4;
  const long m0 = (long)blockIdx.x*64 + w*16;
  const long nb0 = (long)blockIdx.y*64;
  f32x4 acc[4] = {{0,0,0,0},{0,0,0,0},{0,0,0,0},{0,0,0,0}};
  for (int kc = 0; kc < K; kc += 32){
    f16x8 a = *(const f16x8*)(A + (m0 + ml)*ldA + kc + quad*8);
    #pragma unroll
    for (int nt = 0; nt < 4; ++nt){
      f16x8 bfr = *(const f16x8*)(B + (nb0 + nt*16 + ml)*ldB + kc + quad*8);
      acc[nt] = __builtin_amdgcn_mfma_f32_16x16x32_f16(a, bfr, acc[nt], 0, 0, 0);
    }
  }
  #pragma unroll
  for (int nt = 0; nt < 4; ++nt){
    long col = nb0 + nt*16 + ml;
    float bv = (op >= 1) ? bias[col] : 0.0f;
    #pragma unroll
    for (int r = 0; r < 4; ++r){
      float v = acc[nt][r];
      if (op >= 1) v += bv;
      if (op == 2) v = __expf(-fmaxf(v, 0.0f));
      long row = m0 + quad*4 + r;
      C[row*LDP + colofs + col] = (_Float16)v;
    }
  }
}

// ---------- sequential recurrence: 1 block per batch, wave-specialized ----------
#define NTS 1024

struct __align__(16) SeqS {
  f16x8 whist_l[32*128];        // 64 KB [c*128 + j]
  h2 wfcp[128*64];              // 32 KB [k*64 + l] = {Wfc[k][l], Wfc[k][l+64]}
  float h[HT];
  float hs[HT];
  alignas(16) _Float16 hsh[HT];
  float gh[3*HT];
  float gi[3*HT];
  float v3[KT];
  float v5[KT];
  int lidx[KT];
  unsigned gam[128];            // gamma_h(t+1) dwords
  unsigned pbd[2][512];         // P dwords 128..639: [alpha 64 | gipre 384 | zpre 64]
  float xb[2][KT], mb[2][KT];
  float bhist[KT], bfeat[KT];
  float bhh[3*HT];
  float wout[HT];
  float minv[LT];
};

__global__ __launch_bounds__(NTS) void rits_seq(
    const float* __restrict__ x, const float* __restrict__ mask,
    const int* __restrict__ record_num, const float* __restrict__ msumInv,
    const _Float16* __restrict__ P,
    const f16x8* __restrict__ Whh_p, const f16x8* __restrict__ Whist_p,
    const _Float16* __restrict__ Wfc, const _Float16* __restrict__ Wihc,
    const float* __restrict__ b_hist, const float* __restrict__ b_feat,
    const float* __restrict__ b_hh,
    const float* __restrict__ W_out, const float* __restrict__ b_out,
    float* __restrict__ out)
{
  __shared__ SeqS s;
  const int tid = threadIdx.x;
  const int b = blockIdx.x;
  const int rn = record_num[b];
  const unsigned* __restrict__ Pd = (const unsigned*)P + (size_t)b*LT*(LDP/2);

  // ---- init ----
  for (int i = tid; i < 32*128; i += NTS) s.whist_l[i] = Whist_p[i];
  for (int i = tid; i < 128*64; i += NTS){
    int k = i >> 6, l = i & 63;
    h2 w; w[0] = Wfc[k*128 + l]; w[1] = Wfc[k*128 + 64 + l];
    s.wfcp[i] = w;
  }
  if (tid < HT){ s.h[tid] = 0.0f; s.hs[tid] = 0.0f; s.hsh[tid] = (_Float16)0.0f;
                 s.wout[tid] = W_out[tid]; }
  if (tid < KT){ s.bhist[tid] = b_hist[tid]; s.bfeat[tid] = b_feat[tid]; }
  if (tid >= 256 && tid < 256 + 3*HT) s.bhh[tid - 256] = b_hh[tid - 256];
  // t=0 streams
  if (tid >= 64 && tid < 576) s.pbd[0][tid - 64] = Pd[128 + (tid - 64)];
  if (tid >= 576 && tid < 704){
    int k = tid - 576;
    s.xb[0][k] = x[((size_t)b*LT)*KT + k];
    s.mb[0][k] = mask[((size_t)b*LT)*KT + k];
  }
  if (tid >= 704 && tid < 960) s.minv[tid - 704] = msumInv[tid - 704];
  __syncthreads();

  float loss = 0.0f;

  for (int t = 0; t < LT; ++t){
    const int cur = t & 1, nxt = cur ^ 1;
    const int last = (t == LT - 1);

    if (tid < 64){
      // ================= CRIT wave =================
      const int j0 = tid, j1 = tid + 64;
      const float inv = s.minv[t];
      float mv0 = s.mb[cur][j0], mv1 = s.mb[cur][j1];
      float xv0 = s.xb[cur][j0], xv1 = s.xb[cur][j1];
      // list build (ballot rank, dense order)
      bool miss0 = (mv0 == 0.0f), miss1 = (mv1 == 0.0f);
      unsigned long long bal0 = __ballot(miss0);
      unsigned long long bal1 = __ballot(miss1);
      unsigned long long ltm = (1ull << tid) - 1ull;
      int cA = __popcll(bal0);
      int c0 = cA + __popcll(bal1);
      int pos0 = __popcll(bal0 & ltm);
      int pos1 = cA + __popcll(bal1 & ltm);
      if (miss0) s.lidx[pos0] = j0;
      if (miss1) s.lidx[pos1] = j1;
      // xh for j0, j1 (LDS Whist)
      const f16x8* hp = (const f16x8*)s.hsh;
      float A0=0.f,A1=0.f,A2=0.f,A3=0.f,B0=0.f,B1=0.f,B2=0.f,B3=0.f;
      #pragma unroll 8
      for (int c = 0; c < 32; ++c){
        f16x8 av = hp[c];
        f16x8 w0 = s.whist_l[c*128 + j0];
        f16x8 w1 = s.whist_l[c*128 + j1];
        A0 = fd2(lo2(w0), lo2(av), A0); A1 = fd2(p1v(w0), p1v(av), A1);
        A2 = fd2(p2v(w0), p2v(av), A2); A3 = fd2(p3v(w0), p3v(av), A3);
        B0 = fd2(lo2(w1), lo2(av), B0); B1 = fd2(p1v(w1), p1v(av), B1);
        B2 = fd2(p2v(w1), p2v(av), B2); B3 = fd2(p3v(w1), p3v(av), B3);
      }
      float xh0 = (A0+A1)+(A2+A3) + s.bhist[j0];
      float xh1 = (B0+B1)+(B2+B3) + s.bhist[j1];
      loss += (fabsf(xv0 - xh0)*mv0 + fabsf(xv1 - xh1)*mv1) * inv;
      if (miss0) s.v3[pos0] = xh0;
      if (miss1) s.v3[pos1] = xh1;
      // zh (LDS wfcp h2-packed)
      float za0=0.f, za1=0.f, zb0=0.f, zb1=0.f;
      {
        int i = 0;
        for (; i + 1 < c0; i += 2){
          int l0 = s.lidx[i], l1 = s.lidx[i + 1];
          float v0 = s.v3[i], v1 = s.v3[i + 1];
          h2 wa = s.wfcp[l0*64 + tid];
          h2 wb = s.wfcp[l1*64 + tid];
          za0 += v0*(float)wa[0]; za1 += v0*(float)wa[1];
          zb0 += v1*(float)wb[0]; zb1 += v1*(float)wb[1];
        }
        if (i < c0){
          int l0 = s.lidx[i]; float v0 = s.v3[i];
          h2 wa = s.wfcp[l0*64 + tid];
          za0 += v0*(float)wa[0]; za1 += v0*(float)wa[1];
        }
      }
      float z0 = f16bits(s.pbd[cur][448 + (j0 >> 1)], j0 & 1) + s.bfeat[j0] + za0 + zb0;
      float z1 = f16bits(s.pbd[cur][448 + (j1 >> 1)], j1 & 1) + s.bfeat[j1] + za1 + zb1;
      float al0 = f16bits(s.pbd[cur][j0 >> 1], j0 & 1);
      float al1 = f16bits(s.pbd[cur][j1 >> 1], j1 & 1);
      float e = (t < rn) ? 1.0f : 0.0f;
      float ch0 = al0*z0 + (1.0f - al0)*xh0;
      float ch1 = al1*z1 + (1.0f - al1)*xh1;
      loss += ((fabsf(xv0 - z0) + fabsf(xv0 - ch0))*mv0
             + (fabsf(xv1 - z1) + fabsf(xv1 - ch1))*mv1) * e * inv;
      float cc0 = mv0*xv0 + (1.0f - mv0)*ch0;
      float cc1 = mv1*xv1 + (1.0f - mv1)*ch1;
      out[((size_t)b*LT + t)*KT + j0] = cc0 * e;
      out[((size_t)b*LT + t)*KT + j1] = cc1 * e;
      if (miss0) s.v5[pos0] = ch0;
      if (miss1) s.v5[pos1] = ch1;
      // gi: 12 outputs per lane via h2-paired Wihc
      float g[12];
      #pragma unroll
      for (int u = 0; u < 6; ++u){
        int m = tid + 64*u;
        g[u]     = f16bits(s.pbd[cur][64 + (m >> 1)], m & 1);
        int m2 = m + 384;
        g[6 + u] = f16bits(s.pbd[cur][64 + (m2 >> 1)], m2 & 1);
      }
      for (int i = 0; i < c0; ++i){
        float vv = s.v5[i];
        const h2* wr = (const h2*)(Wihc + (size_t)s.lidx[i]*768);
        #pragma unroll
        for (int u = 0; u < 6; ++u){
          h2 w = wr[tid + 64*u];
          g[u]     += vv*(float)w[0];
          g[6 + u] += vv*(float)w[1];
        }
      }
      #pragma unroll
      for (int u = 0; u < 6; ++u){
        s.gi[tid + 64*u]       = g[u];
        s.gi[384 + tid + 64*u] = g[6 + u];
      }
    } else if (tid < 832) {
      // ================= GH waves (768 threads) =================
      const int gj = tid - 64;
      const f16x8* hp = (const f16x8*)s.hsh;
      float a0=0.f, a1=0.f, a2=0.f, a3=0.f;
      #pragma unroll 8
      for (int c = 0; c < 32; ++c){
        f16x8 w = Whh_p[c*768 + gj];
        f16x8 av = hp[c];
        a0 = fd2(lo2(w), lo2(av), a0);
        a1 = fd2(p1v(w), p1v(av), a1);
        a2 = fd2(p2v(w), p2v(av), a2);
        a3 = fd2(p3v(w), p3v(av), a3);
      }
      s.gh[gj] = (a0 + a1) + (a2 + a3);
    } else {
      // ================= PF waves =================
      if (!last){
        int pf = tid - 832;
        const unsigned* Pn = Pd + (size_t)(t + 1)*(LDP/2);
        if (pf < 128){
          s.gam[pf] = Pn[pf];
          #pragma unroll
          for (int u = 0; u < 4; ++u)
            s.pbd[nxt][u*128 + pf] = Pn[128 + u*128 + pf];
        } else {
          int k2 = pf - 128;   // 0..63
          const float2* xp = (const float2*)(x + ((size_t)b*LT + t + 1)*KT);
          const float2* mp = (const float2*)(mask + ((size_t)b*LT + t + 1)*KT);
          float2 xv = xp[k2], mv = mp[k2];
          s.xb[nxt][2*k2] = xv.x;   s.xb[nxt][2*k2 + 1] = xv.y;
          s.mb[nxt][2*k2] = mv.x;   s.mb[nxt][2*k2 + 1] = mv.y;
        }
      }
    }
    __syncthreads();   // B1

    // ================= gates =================
    if (tid < HT){
      const int j = tid;
      float ir = s.gi[j], iz = s.gi[HT + j], ig = s.gi[2*HT + j];
      float hr = s.gh[j] + s.bhh[j];
      float hz = s.gh[HT + j] + s.bhh[HT + j];
      float hg = s.gh[2*HT + j] + s.bhh[2*HT + j];
      float r = sigf(ir + hr);
      float zg = sigf(iz + hz);
      float n = tanh_fast(ig + r*hg);
      float hn = (1.0f - zg)*n + zg*s.hs[j];
      float he = (t < rn) ? hn : s.h[j];
      s.h[j] = he;
      if (!last){
        float gn = f16bits(s.gam[j >> 1], j & 1);
        float hsn = he * gn;
        s.hs[j] = hsn;
        s.hsh[j] = (_Float16)hsn;
      }
    }
    __syncthreads();   // B2
  }

  // ---- loss reduction (CRIT wave only holds loss) ----
  if (tid < 64){
    #pragma unroll
    for (int off = 32; off; off >>= 1) loss += __shfl_down(loss, off);
    if (tid == 0) atomicAdd(&out[LOSS_IDX], loss);
  }

  // ---- prediction ----
  if (tid < HT) s.gi[tid] = s.h[tid] * s.wout[tid];
  __syncthreads();
  for (int st2 = 128; st2 > 0; st2 >>= 1){
    if (tid < st2) s.gi[tid] += s.gi[tid + st2];
    __syncthreads();
  }
  if (tid == 0) out[PRED_IDX + b] = sigf(s.gi[0] + b_out[0]);
}

extern "C" void kernel_launch(void* const* d_in, const int* in_sizes, int n_in,
                              void* d_out, int out_size, void* d_ws, size_t ws_size,
                              hipStream_t stream){
  const float* x      = (const float*)d_in[0];
  const float* mask   = (const float*)d_in[1];
  const float* ts     = (const float*)d_in[2];
  const float* W_gh   = (const float*)d_in[3];
  const float* b_gh   = (const float*)d_in[4];
  const float* W_gx   = (const float*)d_in[5];
  const float* b_gx   = (const float*)d_in[6];
  const float* W_hist = (const float*)d_in[7];
  const float* b_hist = (const float*)d_in[8];
  const float* W_feat = (const float*)d_in[9];
  const float* b_feat = (const float*)d_in[10];
  const float* W_comb = (const float*)d_in[11];
  const float* b_comb = (const float*)d_in[12];
  const float* W_ih   = (const float*)d_in[13];
  const float* W_hh   = (const float*)d_in[14];
  const float* b_ih   = (const float*)d_in[15];
  const float* b_hh   = (const float*)d_in[16];
  const float* W_out  = (const float*)d_in[17];
  const float* b_out  = (const float*)d_in[18];
  const int*   rn     = (const int*)d_in[19];
  float* out = (float*)d_out;
  char* ws = (char*)d_ws;

  size_t off = 0;
  auto alloc = [&](size_t bytes) -> char* {
    char* p = ws + off;
    off += (bytes + 255) & ~(size_t)255;
    return p;
  };
  _Float16* P      = (_Float16*)alloc((size_t)BT*LT*LDP*2);   // 167.8 MB
  _Float16* deltas = (_Float16*)alloc((size_t)BT*LT*KT*2);    // 16.8 MB
  _Float16* Agx    = (_Float16*)alloc((size_t)BT*LT*2*KT*2);  // 33.6 MB
  _Float16* U      = (_Float16*)alloc((size_t)BT*LT*2*KT*2);  // 33.6 MB
  _Float16* WghF   = (_Float16*)alloc(HT*KT*2);
  _Float16* WcombF = (_Float16*)alloc(KT*2*KT*2);
  _Float16* WihF   = (_Float16*)alloc(3*HT*2*KT*2);
  _Float16* WfeatF = (_Float16*)alloc(KT*KT*2);
  _Float16* Whh_p  = (_Float16*)alloc(3*HT*HT*2);
  _Float16* Whist_p= (_Float16*)alloc(KT*HT*2);
  _Float16* Wfc    = (_Float16*)alloc(KT*KT*2);
  _Float16* Wihc   = (_Float16*)alloc(KT*3*HT*2);
  float* msumInv   = (float*)alloc(LT*4);

  auto grid1 = [](int n){ return dim3((n + 255)/256); };
  pack_cast<<<grid1(HT*KT), 256, 0, stream>>>(W_gh, WghF, HT, KT, 0, HT*KT);
  pack_cast<<<grid1(KT*2*KT), 256, 0, stream>>>(W_comb, WcombF, KT, 2*KT, 0, KT*2*KT);
  pack_cast<<<grid1(3*HT*2*KT), 256, 0, stream>>>(W_ih, WihF, 3*HT, 2*KT, 0, 3*HT*2*KT);
  pack_cast<<<grid1(KT*KT), 256, 0, stream>>>(W_feat, WfeatF, KT, KT, 1, KT*KT);
  pack_rowchunks<<<grid1(3*HT*(HT/8)), 256, 0, stream>>>(W_hh, Whh_p, 3*HT, HT, 3*HT*(HT/8));
  pack_rowchunks<<<grid1(KT*(HT/8)), 256, 0, stream>>>(W_hist, Whist_p, KT, HT, KT*(HT/8));
  pack_col<<<grid1(KT*KT), 256, 0, stream>>>(W_feat, Wfc, KT, KT, KT, 1, KT*KT);
  pack_colpair<<<grid1(KT*384), 256, 0, stream>>>(W_ih, Wihc, KT*384);

  scan_kernel<<<dim3(BT), dim3(KT), 0, stream>>>(x, mask, ts, W_gx, b_gx, rn, deltas, Agx, U);
  msum_kernel<<<dim3(LT), dim3(256), 0, stream>>>(mask, msumInv);

  const int MR = BT*LT;
  gemm_f16<<<dim3(MR/64, HT/64), 256, 0, stream>>>(deltas, KT, KT, WghF, KT, P, GH0, b_gh, 2);
  gemm_f16<<<dim3(MR/64, KT/64), 256, 0, stream>>>(Agx, 2*KT, 2*KT, WcombF, 2*KT, P, AL0, b_comb, 1);
  gemm_f16<<<dim3(MR/64, 3*HT/64), 256, 0, stream>>>(U, 2*KT, 2*KT, WihF, 2*KT, P, GI0, b_ih, 1);
  gemm_f16<<<dim3(MR/64, KT/64), 256, 0, stream>>>(U, 2*KT, KT, WfeatF, KT, P, ZP0, (const float*)nullptr, 0);

  hipMemsetAsync((void*)(out + LOSS_IDX), 0, sizeof(float), stream);

  rits_seq<<<dim3(BT), dim3(NTS), 0, stream>>>(x, mask, rn, msumInv, P,
      (const f16x8*)Whh_p, (const f16x8*)Whist_p, Wfc, Wihc,
      b_hist, b_feat, b_hh, W_out, b_out, out);
}